// Round 10
// baseline (169.362 us; speedup 1.0000x reference)
//
#include <hip/hip_runtime.h>
#include <math.h>

#define FEAT 512

// Output layout (float32), flat concat:
//   A_real [1024,256,256] @ 0
//   A_imag [1024,256,256] @ 67108864
//   D_real [1024,16,16]   @ 134217728
//   D_imag [1024,16,16]   @ 134479872
//   C      [256,16]       @ 134742016
#define A_IMAG_OFF 67108864
#define DR_OFF     134217728
#define DI_OFF     134479872
#define C_OFF      134742016
#define THETA_BLOCKS 64           // 16 batch-tiles x 4 col-tiles (64x64)
#define DRDI_BLOCKS  64           // 64 batch-tiles of 16 rows x 512 cols
#define FILL_BLOCKS  8192         // grid-stride over 2*16777216 float4 chunks
#define FILL_STRIDE  (FILL_BLOCKS * 256)   // 2097152 chunks per sweep

typedef __attribute__((ext_vector_type(8))) short bf16x8;
typedef __attribute__((ext_vector_type(4))) float f32x4;

// round-to-nearest-even fp32 -> bf16 bits
__device__ inline short bf16_rne(float f) {
    unsigned u = __float_as_uint(f);
    unsigned r = (u + 0x7FFFu + ((u >> 16) & 1u)) >> 16;
    return (short)r;
}

// split f into hi (bf16) + lo (bf16 of remainder)
__device__ inline void split8(const float* f, bf16x8& hi, bf16x8& lo) {
    #pragma unroll
    for (int j = 0; j < 8; ++j) {
        short h = bf16_rne(f[j]);
        hi[j] = h;
        float hf = __uint_as_float(((unsigned)(unsigned short)h) << 16);
        lo[j] = bf16_rne(f[j] - hf);
    }
}

// ROCclr-style minimal fill: branch-free grid-stride, zero the WHOLE
// A_real+A_imag region (diag chunks included; GEMM overwrites them after).
// Lean VGPR -> max wave occupancy -> max outstanding stores.
__global__ __launch_bounds__(256) void fill_kernel(float* __restrict__ out)
{
    const f32x4 z = {0.f, 0.f, 0.f, 0.f};
    f32x4* p = (f32x4*)out + (size_t)blockIdx.x * 256 + threadIdx.x;
    #pragma unroll
    for (int i = 0; i < 16; ++i) {
        *p = z;
        p += FILL_STRIDE;
    }
}

// GEMM kernel (runs after fill; stream order guarantees zeros are down):
//  blocks [0,64):   theta 64x64 tiles -> sincos -> full 16B diag-chunk stores
//  blocks [64,128): Dr/Di 16x512 tiles -> in-block norm -> scaled stores
//  block 128:       C copy
__global__ __launch_bounds__(256) void gemm_kernel(
    const float* __restrict__ x,
    const float* __restrict__ Wt, const float* __restrict__ bt,
    const float* __restrict__ Wr, const float* __restrict__ br,
    const float* __restrict__ Wi, const float* __restrict__ bi,
    const float* __restrict__ Cin,
    float* __restrict__ out)
{
    __shared__ float red[16][4];
    const int bid = blockIdx.x;
    const int t   = threadIdx.x;

    if (bid >= THETA_BLOCKS + DRDI_BLOCKS) {
        // ---- C copy ----
        #pragma unroll
        for (int i = 0; i < 4; ++i) {
            int q = t + 256 * i;
            *(f32x4*)(out + C_OFF + 4 * q) = *(const f32x4*)(Cin + 4 * q);
        }
        return;
    }

    const int l  = t & 63;
    const int w  = t >> 6;                 // wave id 0..3
    const int lr = l & 15;
    const int kg = l >> 4;                 // k-group (8 consecutive k)

    if (bid < THETA_BLOCKS) {
        // ---------------- theta path: 64-batch x 64-col ----------------
        const int b0 = (bid & 15) * 64;
        const int n0 = (bid >> 4) * 64;
        const int wr = w >> 1, wc = w & 1;
        const int arow0 = b0 + wr * 32 + lr;
        const int bcol0 = n0 + wc * 32 + lr;

        f32x4 acc[2][2] = {};
        for (int f0 = 0; f0 < FEAT; f0 += 32) {
            const int ks = f0 + kg * 8;
            bf16x8 ah[2], al[2], bh[2], bl[2];
            #pragma unroll
            for (int mi = 0; mi < 2; ++mi) {
                const float* p = x + (size_t)(arow0 + mi * 16) * FEAT + ks;
                f32x4 v0 = *(const f32x4*)p, v1 = *(const f32x4*)(p + 4);
                float f[8] = {v0.x, v0.y, v0.z, v0.w, v1.x, v1.y, v1.z, v1.w};
                split8(f, ah[mi], al[mi]);
            }
            #pragma unroll
            for (int ni = 0; ni < 2; ++ni) {
                const float* p = Wt + (size_t)(bcol0 + ni * 16) * FEAT + ks;
                f32x4 v0 = *(const f32x4*)p, v1 = *(const f32x4*)(p + 4);
                float f[8] = {v0.x, v0.y, v0.z, v0.w, v1.x, v1.y, v1.z, v1.w};
                split8(f, bh[ni], bl[ni]);
            }
            #pragma unroll
            for (int mi = 0; mi < 2; ++mi)
                #pragma unroll
                for (int ni = 0; ni < 2; ++ni) {
                    acc[mi][ni] = __builtin_amdgcn_mfma_f32_16x16x32_bf16(ah[mi], bh[ni], acc[mi][ni], 0, 0, 0);
                    acc[mi][ni] = __builtin_amdgcn_mfma_f32_16x16x32_bf16(ah[mi], bl[ni], acc[mi][ni], 0, 0, 0);
                    acc[mi][ni] = __builtin_amdgcn_mfma_f32_16x16x32_bf16(al[mi], bh[ni], acc[mi][ni], 0, 0, 0);
                }
        }
        #pragma unroll
        for (int mi = 0; mi < 2; ++mi)
            #pragma unroll
            for (int ni = 0; ni < 2; ++ni) {
                float bv = bt[bcol0 + ni * 16];
                #pragma unroll
                for (int r = 0; r < 4; ++r) {
                    int b = b0 + wr * 32 + mi * 16 + kg * 4 + r;
                    int m = bcol0 + ni * 16;
                    float s, c;
                    sincosf(acc[mi][ni][r] + bv, &s, &c);
                    f32x4 vr = {0.f, 0.f, 0.f, 0.f};
                    f32x4 vi = {0.f, 0.f, 0.f, 0.f};
                    vr[m & 3] = c;
                    vi[m & 3] = s;
                    size_t off = (size_t)b * 65536 + m * 256 + (m >> 2) * 4;
                    *(f32x4*)(out + off) = vr;
                    *(f32x4*)(out + A_IMAG_OFF + off) = vi;
                }
            }
        return;
    }

    // ---------------- Dr/Di path: 16-batch x 512-col, norm in-block ----------------
    const int b0 = (bid - THETA_BLOCKS) * 16;
    // wave w owns cols [w*128, w*128+128): w<2 -> Dr (Wr/br), w>=2 -> Di (Wi/bi)
    const float* __restrict__ W    = (w < 2) ? Wr : Wi;
    const float* __restrict__ bias = (w < 2) ? br : bi;
    const int c0 = (w & 1) * 128 + lr;     // local col base within the 256-col matrix

    f32x4 acc[8] = {};
    for (int f0 = 0; f0 < FEAT; f0 += 32) {
        const int ks = f0 + kg * 8;
        bf16x8 ah, al, bh[8], bl[8];
        {
            const float* p = x + (size_t)(b0 + lr) * FEAT + ks;
            f32x4 v0 = *(const f32x4*)p, v1 = *(const f32x4*)(p + 4);
            float f[8] = {v0.x, v0.y, v0.z, v0.w, v1.x, v1.y, v1.z, v1.w};
            split8(f, ah, al);
        }
        #pragma unroll
        for (int ni = 0; ni < 8; ++ni) {
            const float* p = W + (size_t)(c0 + ni * 16) * FEAT + ks;
            f32x4 v0 = *(const f32x4*)p, v1 = *(const f32x4*)(p + 4);
            float f[8] = {v0.x, v0.y, v0.z, v0.w, v1.x, v1.y, v1.z, v1.w};
            split8(f, bh[ni], bl[ni]);
        }
        #pragma unroll
        for (int ni = 0; ni < 8; ++ni) {
            acc[ni] = __builtin_amdgcn_mfma_f32_16x16x32_bf16(ah, bh[ni], acc[ni], 0, 0, 0);
            acc[ni] = __builtin_amdgcn_mfma_f32_16x16x32_bf16(ah, bl[ni], acc[ni], 0, 0, 0);
            acc[ni] = __builtin_amdgcn_mfma_f32_16x16x32_bf16(al, bh[ni], acc[ni], 0, 0, 0);
        }
    }
    // bias + per-batch sum of squares over this wave's 128 cols
    float ssq[4];
    #pragma unroll
    for (int r = 0; r < 4; ++r) ssq[r] = 0.f;
    #pragma unroll
    for (int ni = 0; ni < 8; ++ni) {
        float bv = bias[c0 + ni * 16];
        #pragma unroll
        for (int r = 0; r < 4; ++r) {
            acc[ni][r] += bv;
            ssq[r] += acc[ni][r] * acc[ni][r];
        }
    }
    #pragma unroll
    for (int r = 0; r < 4; ++r) {
        ssq[r] += __shfl_xor(ssq[r], 1);
        ssq[r] += __shfl_xor(ssq[r], 2);
        ssq[r] += __shfl_xor(ssq[r], 4);
        ssq[r] += __shfl_xor(ssq[r], 8);
        if (lr == 0) red[kg * 4 + r][w] = ssq[r];
    }
    __syncthreads();
    const size_t base = (w < 2) ? DR_OFF : DI_OFF;
    #pragma unroll
    for (int r = 0; r < 4; ++r) {
        int brow = kg * 4 + r;             // batch within tile
        float sum = red[brow][0] + red[brow][1] + red[brow][2] + red[brow][3];
        float k = 0.7905694150420949f * rsqrtf(sum);   // sqrt(10)/(4*sqrt(sum))
        #pragma unroll
        for (int ni = 0; ni < 8; ++ni)
            out[base + (size_t)(b0 + brow) * 256 + c0 + ni * 16] = acc[ni][r] * k;
    }
}

extern "C" void kernel_launch(void* const* d_in, const int* in_sizes, int n_in,
                              void* d_out, int out_size, void* d_ws, size_t ws_size,
                              hipStream_t stream)
{
    const float* x  = (const float*)d_in[0];
    const float* Wt = (const float*)d_in[1];
    const float* bt = (const float*)d_in[2];
    const float* Wr = (const float*)d_in[3];
    const float* br = (const float*)d_in[4];
    const float* Wi = (const float*)d_in[5];
    const float* bi = (const float*)d_in[6];
    const float* C  = (const float*)d_in[7];
    float* out = (float*)d_out;

    // 1) lean branch-free fill of the whole A region (incl. diag chunks)
    fill_kernel<<<FILL_BLOCKS, 256, 0, stream>>>(out);

    // 2) GEMM overwrites diag chunks, writes scaled Dr/Di + C
    gemm_kernel<<<THETA_BLOCKS + DRDI_BLOCKS + 1, 256, 0, stream>>>(
        x, Wt, bt, Wr, br, Wi, bi, C, out);
}

// Round 11
// 125.411 us; speedup vs baseline: 1.3505x; 1.3505x over previous
//
#include <hip/hip_runtime.h>
#include <math.h>

#define FEAT 512

// Output layout (float32), flat concat:
//   A_real [1024,256,256] @ 0
//   A_imag [1024,256,256] @ 67108864
//   D_real [1024,16,16]   @ 134217728
//   D_imag [1024,16,16]   @ 134479872
//   C      [256,16]       @ 134742016
#define A_IMAG_OFF 67108864
#define DR_OFF     134217728
#define DI_OFF     134479872
#define C_OFF      134742016
#define NFILL4       16777216     // float4 count per A matrix
#define THETA_BLOCKS 64           // 16 batch-tiles x 4 col-tiles (64x64)
#define DRDI_BLOCKS  64           // 64 batch-tiles of 16 rows x 512 cols
#define GEMM_BLOCKS  (THETA_BLOCKS + DRDI_BLOCKS)
#define FILL_BLOCKS  (NFILL4 / 256)   // 65536, one float4 chunk per matrix per thread

typedef __attribute__((ext_vector_type(8))) short bf16x8;
typedef __attribute__((ext_vector_type(4))) float f32x4;

// round-to-nearest-even fp32 -> bf16 bits
__device__ inline short bf16_rne(float f) {
    unsigned u = __float_as_uint(f);
    unsigned r = (u + 0x7FFFu + ((u >> 16) & 1u)) >> 16;
    return (short)r;
}

// split f into hi (bf16) + lo (bf16 of remainder)
__device__ inline void split8(const float* f, bf16x8& hi, bf16x8& lo) {
    #pragma unroll
    for (int j = 0; j < 8; ++j) {
        short h = bf16_rne(f[j]);
        hi[j] = h;
        float hf = __uint_as_float(((unsigned)(unsigned short)h) << 16);
        lo[j] = bf16_rne(f[j] - hf);
    }
}

// Single fused kernel (best structure, R8):
//  blocks [0,64):            theta GEMM 64x64 tiles -> sincos -> full 16B diag chunks
//  blocks [64,128):          Dr/Di GEMM 16x512 tiles -> in-block norm -> scaled stores
//  blocks [128,128+65536):   A off-diagonal zero fill (2 cached float4 stores/thread)
//  last block:               C copy
__global__ __launch_bounds__(256) void fused_kernel(
    const float* __restrict__ x,
    const float* __restrict__ Wt, const float* __restrict__ bt,
    const float* __restrict__ Wr, const float* __restrict__ br,
    const float* __restrict__ Wi, const float* __restrict__ bi,
    const float* __restrict__ Cin,
    float* __restrict__ out)
{
    __shared__ float red[16][4];
    const int bid = blockIdx.x;
    const int t   = threadIdx.x;

    if (bid >= GEMM_BLOCKS) {
        const int fb = bid - GEMM_BLOCKS;
        if (fb >= FILL_BLOCKS) {
            // ---- C copy ----
            #pragma unroll
            for (int i = 0; i < 4; ++i) {
                int q = t + 256 * i;
                *(f32x4*)(out + C_OFF + 4 * q) = *(const f32x4*)(Cin + 4 * q);
            }
            return;
        }
        // ---- A off-diagonal zero fill ----
        const int idx = fb * 256 + t;          // float4 index within one A matrix
        const int c4  = idx & 63;
        const int m   = (idx >> 6) & 255;
        if (c4 == (m >> 2)) return;            // diagonal chunk: theta blocks own it
        const f32x4 z = {0.f, 0.f, 0.f, 0.f};
        *(f32x4*)(out + 4 * (size_t)idx) = z;
        *(f32x4*)(out + A_IMAG_OFF + 4 * (size_t)idx) = z;
        return;
    }

    const int l  = t & 63;
    const int w  = t >> 6;                 // wave id 0..3
    const int lr = l & 15;
    const int kg = l >> 4;                 // k-group (8 consecutive k)

    if (bid < THETA_BLOCKS) {
        // ---------------- theta path: 64-batch x 64-col ----------------
        const int b0 = (bid & 15) * 64;
        const int n0 = (bid >> 4) * 64;
        const int wr = w >> 1, wc = w & 1;
        const int arow0 = b0 + wr * 32 + lr;
        const int bcol0 = n0 + wc * 32 + lr;

        f32x4 acc[2][2] = {};
        for (int f0 = 0; f0 < FEAT; f0 += 32) {
            const int ks = f0 + kg * 8;
            bf16x8 ah[2], al[2], bh[2], bl[2];
            #pragma unroll
            for (int mi = 0; mi < 2; ++mi) {
                const float* p = x + (size_t)(arow0 + mi * 16) * FEAT + ks;
                f32x4 v0 = *(const f32x4*)p, v1 = *(const f32x4*)(p + 4);
                float f[8] = {v0.x, v0.y, v0.z, v0.w, v1.x, v1.y, v1.z, v1.w};
                split8(f, ah[mi], al[mi]);
            }
            #pragma unroll
            for (int ni = 0; ni < 2; ++ni) {
                const float* p = Wt + (size_t)(bcol0 + ni * 16) * FEAT + ks;
                f32x4 v0 = *(const f32x4*)p, v1 = *(const f32x4*)(p + 4);
                float f[8] = {v0.x, v0.y, v0.z, v0.w, v1.x, v1.y, v1.z, v1.w};
                split8(f, bh[ni], bl[ni]);
            }
            #pragma unroll
            for (int mi = 0; mi < 2; ++mi)
                #pragma unroll
                for (int ni = 0; ni < 2; ++ni) {
                    acc[mi][ni] = __builtin_amdgcn_mfma_f32_16x16x32_bf16(ah[mi], bh[ni], acc[mi][ni], 0, 0, 0);
                    acc[mi][ni] = __builtin_amdgcn_mfma_f32_16x16x32_bf16(ah[mi], bl[ni], acc[mi][ni], 0, 0, 0);
                    acc[mi][ni] = __builtin_amdgcn_mfma_f32_16x16x32_bf16(al[mi], bh[ni], acc[mi][ni], 0, 0, 0);
                }
        }
        #pragma unroll
        for (int mi = 0; mi < 2; ++mi)
            #pragma unroll
            for (int ni = 0; ni < 2; ++ni) {
                float bv = bt[bcol0 + ni * 16];
                #pragma unroll
                for (int r = 0; r < 4; ++r) {
                    int b = b0 + wr * 32 + mi * 16 + kg * 4 + r;
                    int m = bcol0 + ni * 16;
                    float s, c;
                    sincosf(acc[mi][ni][r] + bv, &s, &c);
                    f32x4 vr = {0.f, 0.f, 0.f, 0.f};
                    f32x4 vi = {0.f, 0.f, 0.f, 0.f};
                    vr[m & 3] = c;
                    vi[m & 3] = s;
                    size_t off = (size_t)b * 65536 + m * 256 + (m >> 2) * 4;
                    *(f32x4*)(out + off) = vr;
                    *(f32x4*)(out + A_IMAG_OFF + off) = vi;
                }
            }
        return;
    }

    // ---------------- Dr/Di path: 16-batch x 512-col, norm in-block ----------------
    const int b0 = (bid - THETA_BLOCKS) * 16;
    // wave w owns cols [w*128, w*128+128): w<2 -> Dr (Wr/br), w>=2 -> Di (Wi/bi)
    const float* __restrict__ W    = (w < 2) ? Wr : Wi;
    const float* __restrict__ bias = (w < 2) ? br : bi;
    const int c0 = (w & 1) * 128 + lr;     // local col base within the 256-col matrix

    f32x4 acc[8] = {};
    for (int f0 = 0; f0 < FEAT; f0 += 32) {
        const int ks = f0 + kg * 8;
        bf16x8 ah, al, bh[8], bl[8];
        {
            const float* p = x + (size_t)(b0 + lr) * FEAT + ks;
            f32x4 v0 = *(const f32x4*)p, v1 = *(const f32x4*)(p + 4);
            float f[8] = {v0.x, v0.y, v0.z, v0.w, v1.x, v1.y, v1.z, v1.w};
            split8(f, ah, al);
        }
        #pragma unroll
        for (int ni = 0; ni < 8; ++ni) {
            const float* p = W + (size_t)(c0 + ni * 16) * FEAT + ks;
            f32x4 v0 = *(const f32x4*)p, v1 = *(const f32x4*)(p + 4);
            float f[8] = {v0.x, v0.y, v0.z, v0.w, v1.x, v1.y, v1.z, v1.w};
            split8(f, bh[ni], bl[ni]);
        }
        #pragma unroll
        for (int ni = 0; ni < 8; ++ni) {
            acc[ni] = __builtin_amdgcn_mfma_f32_16x16x32_bf16(ah, bh[ni], acc[ni], 0, 0, 0);
            acc[ni] = __builtin_amdgcn_mfma_f32_16x16x32_bf16(ah, bl[ni], acc[ni], 0, 0, 0);
            acc[ni] = __builtin_amdgcn_mfma_f32_16x16x32_bf16(al, bh[ni], acc[ni], 0, 0, 0);
        }
    }
    // bias + per-batch sum of squares over this wave's 128 cols
    float ssq[4];
    #pragma unroll
    for (int r = 0; r < 4; ++r) ssq[r] = 0.f;
    #pragma unroll
    for (int ni = 0; ni < 8; ++ni) {
        float bv = bias[c0 + ni * 16];
        #pragma unroll
        for (int r = 0; r < 4; ++r) {
            acc[ni][r] += bv;
            ssq[r] += acc[ni][r] * acc[ni][r];
        }
    }
    #pragma unroll
    for (int r = 0; r < 4; ++r) {
        ssq[r] += __shfl_xor(ssq[r], 1);
        ssq[r] += __shfl_xor(ssq[r], 2);
        ssq[r] += __shfl_xor(ssq[r], 4);
        ssq[r] += __shfl_xor(ssq[r], 8);
        if (lr == 0) red[kg * 4 + r][w] = ssq[r];
    }
    __syncthreads();
    const size_t base = (w < 2) ? DR_OFF : DI_OFF;
    #pragma unroll
    for (int r = 0; r < 4; ++r) {
        int brow = kg * 4 + r;             // batch within tile
        float sum = red[brow][0] + red[brow][1] + red[brow][2] + red[brow][3];
        float k = 0.7905694150420949f * rsqrtf(sum);   // sqrt(10)/(4*sqrt(sum))
        #pragma unroll
        for (int ni = 0; ni < 8; ++ni)
            out[base + (size_t)(b0 + brow) * 256 + c0 + ni * 16] = acc[ni][r] * k;
    }
}

extern "C" void kernel_launch(void* const* d_in, const int* in_sizes, int n_in,
                              void* d_out, int out_size, void* d_ws, size_t ws_size,
                              hipStream_t stream)
{
    const float* x  = (const float*)d_in[0];
    const float* Wt = (const float*)d_in[1];
    const float* bt = (const float*)d_in[2];
    const float* Wr = (const float*)d_in[3];
    const float* br = (const float*)d_in[4];
    const float* Wi = (const float*)d_in[5];
    const float* bi = (const float*)d_in[6];
    const float* C  = (const float*)d_in[7];
    float* out = (float*)d_out;

    fused_kernel<<<GEMM_BLOCKS + FILL_BLOCKS + 1, 256, 0, stream>>>(
        x, Wt, bt, Wr, br, Wi, bi, C, out);
}